// Round 4
// baseline (1669.654 us; speedup 1.0000x reference)
//
#include <hip/hip_runtime.h>
#include <hip/hip_bf16.h>
#include <cstdint>
#include <cstddef>

#define N_NODES 100000
#define N_EDGES 3200000
#define D 256
#define SCAN_BLOCKS 391   // ceil(100000/256)

typedef __attribute__((ext_vector_type(8))) short short8;   // 8 bf16 = 4 VGPRs
typedef __attribute__((ext_vector_type(4))) float f32x4;

typedef __attribute__((address_space(1))) const unsigned char glob_b;
typedef __attribute__((address_space(3))) unsigned char lds_b;

__device__ inline unsigned short f2bf(float f) {            // RNE fp32->bf16
    unsigned int u = __float_as_uint(f);
    u += 0x7FFFu + ((u >> 16) & 1u);
    return (unsigned short)(u >> 16);
}
__device__ inline float bf2f(unsigned short h) {
    return __uint_as_float(((unsigned int)h) << 16);
}

// ---------------------------------------------------------------------------
// CSR build: count -> scan -> fill    (edge_index arrives as int32!)
// ---------------------------------------------------------------------------
__global__ void count_kernel(const int* __restrict__ tgt, int* __restrict__ cnt) {
    int e = blockIdx.x * blockDim.x + threadIdx.x;
    if (e < N_EDGES) {
        int t = tgt[e];
        if (t >= 0 && t < N_NODES) atomicAdd(&cnt[t], 1);
    }
}

__global__ void scan1_kernel(const int* __restrict__ cnt, int* __restrict__ offs,
                             int* __restrict__ bsum) {
    __shared__ int s[256];
    int t = threadIdx.x;
    int i = blockIdx.x * 256 + t;
    int v = (i < N_NODES) ? cnt[i] : 0;
    s[t] = v;
    __syncthreads();
    for (int d = 1; d < 256; d <<= 1) {
        int x = (t >= d) ? s[t - d] : 0;
        __syncthreads();
        s[t] += x;
        __syncthreads();
    }
    if (i < N_NODES) offs[i + 1] = s[t];
    if (t == 255) bsum[blockIdx.x] = s[255];
}

__global__ void scan2_kernel(int* __restrict__ bsum) {
    __shared__ int s[512];
    int t = threadIdx.x;
    int v = (t < SCAN_BLOCKS) ? bsum[t] : 0;
    s[t] = v;
    __syncthreads();
    for (int d = 1; d < 512; d <<= 1) {
        int x = (t >= d) ? s[t - d] : 0;
        __syncthreads();
        s[t] += x;
        __syncthreads();
    }
    if (t < SCAN_BLOCKS) bsum[t] = (t == 0) ? 0 : s[t - 1];
}

__global__ void scan3_kernel(int* __restrict__ offs, const int* __restrict__ bsum) {
    int t = threadIdx.x;
    int i = blockIdx.x * 256 + t;
    if (i < N_NODES) offs[i + 1] += bsum[blockIdx.x];
    if (i == 0) offs[0] = 0;
}

__global__ void cursor_kernel(const int* __restrict__ offs, int* __restrict__ cursor) {
    int i = blockIdx.x * 256 + threadIdx.x;
    if (i < N_NODES) cursor[i] = offs[i];
}

__global__ void fill_kernel(const int* __restrict__ src,
                            const int* __restrict__ tgt,
                            int* __restrict__ cursor, int* __restrict__ sorted_src) {
    int e = blockIdx.x * blockDim.x + threadIdx.x;
    if (e < N_EDGES) {
        int t = tgt[e];
        int s = src[e];
        if (t >= 0 && t < N_NODES && s >= 0 && s < N_NODES) {
            int p = atomicAdd(&cursor[t], 1);
            sorted_src[p] = s;
        }
    }
}

// ---------------------------------------------------------------------------
// fp32 -> bf16 bulk convert (8 elements / thread)
// ---------------------------------------------------------------------------
__global__ __launch_bounds__(256) void convert_kernel(const float* __restrict__ in,
                                                      unsigned short* __restrict__ out,
                                                      int n8) {
    int i = blockIdx.x * 256 + threadIdx.x;
    if (i >= n8) return;
    const float4 a = ((const float4*)in)[i * 2 + 0];
    const float4 b = ((const float4*)in)[i * 2 + 1];
    short8 v;
    v[0] = (short)f2bf(a.x); v[1] = (short)f2bf(a.y);
    v[2] = (short)f2bf(a.z); v[3] = (short)f2bf(a.w);
    v[4] = (short)f2bf(b.x); v[5] = (short)f2bf(b.y);
    v[6] = (short)f2bf(b.z); v[7] = (short)f2bf(b.w);
    ((short8*)out)[i] = v;
}

// ---------------------------------------------------------------------------
// Pack B=[Wl;Wr] (512x256 fp32 row-major) into MFMA B-fragment order, bf16.
// Bp[((ntile*16 + kb)*64 + lane)*8 + j] = B[kb*32 + (lane>>4)*8 + j][ntile*16 + (lane&15)]
// ---------------------------------------------------------------------------
__global__ __launch_bounds__(256) void pack_b_kernel(const float* __restrict__ Wl,
                                                     const float* __restrict__ Wr,
                                                     unsigned short* __restrict__ Bp) {
    int t = blockIdx.x * 256 + threadIdx.x;   // 16*16*64 = 16384
    if (t >= 16384) return;
    int lane = t & 63, kb = (t >> 6) & 15, ntile = t >> 10;
    int n = ntile * 16 + (lane & 15);
    int kbase = kb * 32 + (lane >> 4) * 8;
    short8 v;
#pragma unroll
    for (int j = 0; j < 8; ++j) {
        int k = kbase + j;
        const float* W = (k < 256) ? Wl : Wr;
        v[j] = (short)f2bf(W[(size_t)(k & 255) * D + n]);
    }
    ((short8*)Bp)[t] = v;
}

// ---------------------------------------------------------------------------
// Column-sliced mean aggregation, XCD-pinned.
// g = blockIdx.x & 7 selects a 32-col (64 B) slice; consecutive blocks
// round-robin XCDs, so slice g lives on XCD g -> per-XCD gather working set
// shrinks from 51 MB to 6.4 MB (~L2-resident).
// Wave = 16 nodes x 4 lanes; lane loads 16 B (8 bf16) per edge; 2-edge unroll.
// ---------------------------------------------------------------------------
__global__ __launch_bounds__(256) void aggregate_sliced(
    const unsigned short* __restrict__ in, unsigned short* __restrict__ out,
    const int* __restrict__ offs, const int* __restrict__ sorted_src) {
    const int g = blockIdx.x & 7;
    const int nb = blockIdx.x >> 3;
    const int t = threadIdx.x;
    const int wave = t >> 6, lane = t & 63;
    const int nl = lane >> 2, c = lane & 3;
    const int node = nb * 64 + wave * 16 + nl;
    if (node >= N_NODES) return;
    const int beg = offs[node], end = offs[node + 1];
    const unsigned short* base = in + g * 32 + c * 8;

    float a0 = 0.f, a1 = 0.f, a2 = 0.f, a3 = 0.f;
    float a4 = 0.f, a5 = 0.f, a6 = 0.f, a7 = 0.f;
    int j = beg;
    for (; j + 1 < end; j += 2) {
        int s0 = sorted_src[j];
        int s1 = sorted_src[j + 1];
        short8 v0 = *(const short8*)(base + (size_t)s0 * D);
        short8 v1 = *(const short8*)(base + (size_t)s1 * D);
        a0 += bf2f((unsigned short)v0[0]) + bf2f((unsigned short)v1[0]);
        a1 += bf2f((unsigned short)v0[1]) + bf2f((unsigned short)v1[1]);
        a2 += bf2f((unsigned short)v0[2]) + bf2f((unsigned short)v1[2]);
        a3 += bf2f((unsigned short)v0[3]) + bf2f((unsigned short)v1[3]);
        a4 += bf2f((unsigned short)v0[4]) + bf2f((unsigned short)v1[4]);
        a5 += bf2f((unsigned short)v0[5]) + bf2f((unsigned short)v1[5]);
        a6 += bf2f((unsigned short)v0[6]) + bf2f((unsigned short)v1[6]);
        a7 += bf2f((unsigned short)v0[7]) + bf2f((unsigned short)v1[7]);
    }
    if (j < end) {
        int s0 = sorted_src[j];
        short8 v0 = *(const short8*)(base + (size_t)s0 * D);
        a0 += bf2f((unsigned short)v0[0]); a1 += bf2f((unsigned short)v0[1]);
        a2 += bf2f((unsigned short)v0[2]); a3 += bf2f((unsigned short)v0[3]);
        a4 += bf2f((unsigned short)v0[4]); a5 += bf2f((unsigned short)v0[5]);
        a6 += bf2f((unsigned short)v0[6]); a7 += bf2f((unsigned short)v0[7]);
    }
    float inv = 1.0f / fmaxf((float)(end - beg), 1.0f);
    short8 r;
    r[0] = (short)f2bf(a0 * inv); r[1] = (short)f2bf(a1 * inv);
    r[2] = (short)f2bf(a2 * inv); r[3] = (short)f2bf(a3 * inv);
    r[4] = (short)f2bf(a4 * inv); r[5] = (short)f2bf(a5 * inv);
    r[6] = (short)f2bf(a6 * inv); r[7] = (short)f2bf(a7 * inv);
    *(short8*)(out + (size_t)node * D + g * 32 + c * 8) = r;
}

// ---------------------------------------------------------------------------
// MFMA GEMM: out = [A0 | A1] @ Bp + bias, K=512. BM=64, BN=256 (full width),
// 256 thr = 4 waves; wave w computes 64 rows x cols [w*64, w*64+64).
// A staged via global_load_lds dwordx4 into unpadded [64][32] LDS (layout
// matches lane order exactly; frag ds_read_b128 hits the b128 floor).
// B fragments read from L2-resident packed buffer.
// ---------------------------------------------------------------------------
__global__ __launch_bounds__(256) void gemm_mfma(
    const unsigned short* __restrict__ A0, const unsigned short* __restrict__ A1,
    const unsigned short* __restrict__ Bp, const float* __restrict__ bias,
    void* __restrict__ outp, int relu, int out_bf16) {
    __shared__ unsigned short As[64 * 32];   // 4 KB
    const int m0 = blockIdx.x * 64;
    const int t = threadIdx.x;
    const int wave = t >> 6, lane = t & 63;
    const int quad = lane >> 4, l16 = lane & 15;

    // staging source: thread t covers row t>>2, 16B-quarter t&3 (clamped rows)
    int srow = t >> 2;
    int sq = t & 3;
    int grow = m0 + srow;
    if (grow >= N_NODES) grow = N_NODES - 1;   // clamp; extra rows never stored
    lds_b* ldsbase = (lds_b*)&As[wave * 512];  // 1 KB per wave, uniform per wave

    f32x4 acc[4][4] = {};
    const short8* Bp8 = (const short8*)Bp;

    for (int kb = 0; kb < 16; ++kb) {
        const unsigned short* A = (kb < 8) ? A0 : A1;
        const int kk = (kb * 32) & 255;
        const unsigned short* gp = A + (size_t)grow * D + kk + sq * 8;
        __builtin_amdgcn_global_load_lds((glob_b*)gp, ldsbase, 16, 0, 0);
        __syncthreads();

        short8 af[4], bf[4];
#pragma unroll
        for (int mi = 0; mi < 4; ++mi)
            af[mi] = *(const short8*)&As[(mi * 16 + l16) * 32 + quad * 8];
#pragma unroll
        for (int ni = 0; ni < 4; ++ni) {
            int ntile = wave * 4 + ni;
            bf[ni] = Bp8[(size_t)(ntile * 16 + kb) * 64 + lane];
        }
#pragma unroll
        for (int mi = 0; mi < 4; ++mi)
#pragma unroll
            for (int ni = 0; ni < 4; ++ni)
                acc[mi][ni] = __builtin_amdgcn_mfma_f32_16x16x32_bf16(
                    af[mi], bf[ni], acc[mi][ni], 0, 0, 0);
        __syncthreads();
    }

    unsigned short* ob = (unsigned short*)outp;
    float* of = (float*)outp;
#pragma unroll
    for (int ni = 0; ni < 4; ++ni) {
        const int col = wave * 64 + ni * 16 + l16;
        const float bcol = bias[col];
#pragma unroll
        for (int mi = 0; mi < 4; ++mi) {
#pragma unroll
            for (int r = 0; r < 4; ++r) {
                int row = m0 + mi * 16 + quad * 4 + r;
                if (row < N_NODES) {
                    float v = acc[mi][ni][r] + bcol;
                    if (relu) v = fmaxf(v, 0.f);
                    if (out_bf16) ob[(size_t)row * D + col] = f2bf(v);
                    else          of[(size_t)row * D + col] = v;
                }
            }
        }
    }
}

// ---------------------------------------------------------------------------
extern "C" void kernel_launch(void* const* d_in, const int* in_sizes, int n_in,
                              void* d_out, int out_size, void* d_ws, size_t ws_size,
                              hipStream_t stream) {
    const float* x    = (const float*)d_in[0];
    const int*   ei   = (const int*)d_in[1];   // int32 on device!
    const float* W_l1 = (const float*)d_in[2];
    const float* b1   = (const float*)d_in[3];
    const float* W_r1 = (const float*)d_in[4];
    const float* W_l2 = (const float*)d_in[5];
    const float* b2   = (const float*)d_in[6];
    const float* W_r2 = (const float*)d_in[7];
    float* out = (float*)d_out;

    const int* src = ei;
    const int* tgt = ei + N_EDGES;

    char* w = (char*)d_ws;
    size_t o = 0;
    auto alloc = [&](size_t bytes) {
        size_t p = o;
        o = (o + bytes + 255) & ~(size_t)255;
        return p;
    };
    int* cnt        = (int*)(w + alloc((size_t)N_NODES * 4));
    int* offs       = (int*)(w + alloc((size_t)(N_NODES + 1) * 4));
    int* cursor     = (int*)(w + alloc((size_t)N_NODES * 4));
    int* bsum       = (int*)(w + alloc(512 * 4));
    int* sorted_src = (int*)(w + alloc((size_t)N_EDGES * 4));
    unsigned short* xb   = (unsigned short*)(w + alloc((size_t)N_NODES * D * 2));
    unsigned short* hb   = (unsigned short*)(w + alloc((size_t)N_NODES * D * 2));
    unsigned short* aggb = (unsigned short*)(w + alloc((size_t)N_NODES * D * 2));
    unsigned short* Bp1  = (unsigned short*)(w + alloc((size_t)512 * D * 2));
    unsigned short* Bp2  = (unsigned short*)(w + alloc((size_t)512 * D * 2));
    (void)ws_size; (void)in_sizes; (void)n_in; (void)out_size;

    hipMemsetAsync(cnt, 0, (size_t)N_NODES * 4, stream);

    const int EB = (N_EDGES + 255) / 256;
    count_kernel<<<EB, 256, 0, stream>>>(tgt, cnt);
    scan1_kernel<<<SCAN_BLOCKS, 256, 0, stream>>>(cnt, offs, bsum);
    scan2_kernel<<<1, 512, 0, stream>>>(bsum);
    scan3_kernel<<<SCAN_BLOCKS, 256, 0, stream>>>(offs, bsum);
    cursor_kernel<<<SCAN_BLOCKS, 256, 0, stream>>>(offs, cursor);
    fill_kernel<<<EB, 256, 0, stream>>>(src, tgt, cursor, sorted_src);

    // bf16 conversions / weight packing
    const int n8 = N_NODES * D / 8;
    convert_kernel<<<(n8 + 255) / 256, 256, 0, stream>>>(x, xb, n8);
    pack_b_kernel<<<64, 256, 0, stream>>>(W_l1, W_r1, Bp1);
    pack_b_kernel<<<64, 256, 0, stream>>>(W_l2, W_r2, Bp2);

    const int NODE_BLKS = (N_NODES + 63) / 64;   // 1563
    const int AGG_B = NODE_BLKS * 8;             // 12504 (g = blockIdx & 7)
    const int GEMM_B = NODE_BLKS;                // 1563

    // Layer 1
    aggregate_sliced<<<AGG_B, 256, 0, stream>>>(xb, aggb, offs, sorted_src);
    gemm_mfma<<<GEMM_B, 256, 0, stream>>>(aggb, xb, Bp1, b1, hb, 1, 1);

    // Layer 2
    aggregate_sliced<<<AGG_B, 256, 0, stream>>>(hb, aggb, offs, sorted_src);
    gemm_mfma<<<GEMM_B, 256, 0, stream>>>(aggb, hb, Bp2, b2, out, 0, 0);
}

// Round 5
// 1397.111 us; speedup vs baseline: 1.1951x; 1.1951x over previous
//
#include <hip/hip_runtime.h>
#include <hip/hip_bf16.h>
#include <cstdint>
#include <cstddef>

#define N_NODES 100000
#define N_EDGES 3200000
#define D 256
#define SCAN_BLOCKS 391   // ceil(100000/256)

typedef __attribute__((ext_vector_type(8))) short short8;   // 8 bf16 = 4 VGPRs
typedef __attribute__((ext_vector_type(4))) float f32x4;

typedef __attribute__((address_space(1))) const unsigned char glob_b;
typedef __attribute__((address_space(3))) unsigned char lds_b;

__device__ inline unsigned short f2bf(float f) {            // RNE fp32->bf16
    unsigned int u = __float_as_uint(f);
    u += 0x7FFFu + ((u >> 16) & 1u);
    return (unsigned short)(u >> 16);
}
__device__ inline float bf2f(unsigned short h) {
    return __uint_as_float(((unsigned int)h) << 16);
}

// ---------------------------------------------------------------------------
// CSR build: count -> scan -> fill    (edge_index arrives as int32!)
// ---------------------------------------------------------------------------
__global__ void count_kernel(const int* __restrict__ tgt, int* __restrict__ cnt) {
    int e = blockIdx.x * blockDim.x + threadIdx.x;
    if (e < N_EDGES) {
        int t = tgt[e];
        if (t >= 0 && t < N_NODES) atomicAdd(&cnt[t], 1);
    }
}

__global__ void scan1_kernel(const int* __restrict__ cnt, int* __restrict__ offs,
                             int* __restrict__ bsum) {
    __shared__ int s[256];
    int t = threadIdx.x;
    int i = blockIdx.x * 256 + t;
    int v = (i < N_NODES) ? cnt[i] : 0;
    s[t] = v;
    __syncthreads();
    for (int d = 1; d < 256; d <<= 1) {
        int x = (t >= d) ? s[t - d] : 0;
        __syncthreads();
        s[t] += x;
        __syncthreads();
    }
    if (i < N_NODES) offs[i + 1] = s[t];
    if (t == 255) bsum[blockIdx.x] = s[255];
}

__global__ void scan2_kernel(int* __restrict__ bsum) {
    __shared__ int s[512];
    int t = threadIdx.x;
    int v = (t < SCAN_BLOCKS) ? bsum[t] : 0;
    s[t] = v;
    __syncthreads();
    for (int d = 1; d < 512; d <<= 1) {
        int x = (t >= d) ? s[t - d] : 0;
        __syncthreads();
        s[t] += x;
        __syncthreads();
    }
    if (t < SCAN_BLOCKS) bsum[t] = (t == 0) ? 0 : s[t - 1];
}

__global__ void scan3_kernel(int* __restrict__ offs, const int* __restrict__ bsum) {
    int t = threadIdx.x;
    int i = blockIdx.x * 256 + t;
    if (i < N_NODES) offs[i + 1] += bsum[blockIdx.x];
    if (i == 0) offs[0] = 0;
}

__global__ void cursor_kernel(const int* __restrict__ offs, int* __restrict__ cursor) {
    int i = blockIdx.x * 256 + threadIdx.x;
    if (i < N_NODES) cursor[i] = offs[i];
}

__global__ void fill_kernel(const int* __restrict__ src,
                            const int* __restrict__ tgt,
                            int* __restrict__ cursor, int* __restrict__ sorted_src) {
    int e = blockIdx.x * blockDim.x + threadIdx.x;
    if (e < N_EDGES) {
        int t = tgt[e];
        int s = src[e];
        if (t >= 0 && t < N_NODES && s >= 0 && s < N_NODES) {
            int p = atomicAdd(&cursor[t], 1);
            sorted_src[p] = s;
        }
    }
}

// ---------------------------------------------------------------------------
// fp32 -> bf16 bulk convert (8 elements / thread)
// ---------------------------------------------------------------------------
__global__ __launch_bounds__(256) void convert_kernel(const float* __restrict__ in,
                                                      unsigned short* __restrict__ out,
                                                      int n8) {
    int i = blockIdx.x * 256 + threadIdx.x;
    if (i >= n8) return;
    const float4 a = ((const float4*)in)[i * 2 + 0];
    const float4 b = ((const float4*)in)[i * 2 + 1];
    short8 v;
    v[0] = (short)f2bf(a.x); v[1] = (short)f2bf(a.y);
    v[2] = (short)f2bf(a.z); v[3] = (short)f2bf(a.w);
    v[4] = (short)f2bf(b.x); v[5] = (short)f2bf(b.y);
    v[6] = (short)f2bf(b.z); v[7] = (short)f2bf(b.w);
    ((short8*)out)[i] = v;
}

// ---------------------------------------------------------------------------
// Pack B=[Wl;Wr] (512x256 fp32 row-major) into MFMA B-fragment order, bf16.
// Bp[((ntile*16 + kb)*64 + lane)*8 + j] = B[kb*32 + (lane>>4)*8 + j][ntile*16 + (lane&15)]
// ---------------------------------------------------------------------------
__global__ __launch_bounds__(256) void pack_b_kernel(const float* __restrict__ Wl,
                                                     const float* __restrict__ Wr,
                                                     unsigned short* __restrict__ Bp) {
    int t = blockIdx.x * 256 + threadIdx.x;   // 16*16*64 = 16384
    if (t >= 16384) return;
    int lane = t & 63, kb = (t >> 6) & 15, ntile = t >> 10;
    int n = ntile * 16 + (lane & 15);
    int kbase = kb * 32 + (lane >> 4) * 8;
    short8 v;
#pragma unroll
    for (int j = 0; j < 8; ++j) {
        int k = kbase + j;
        const float* W = (k < 256) ? Wl : Wr;
        v[j] = (short)f2bf(W[(size_t)(k & 255) * D + n]);
    }
    ((short8*)Bp)[t] = v;
}

// ---------------------------------------------------------------------------
// Mean aggregation over bf16 rows: one wave per node, lane covers 4 bf16 (8 B).
// Full-row gathers are L2-line-exact (round-4 column slicing caused 2x
// overfetch: 64 B slice of a 128 B line).
// ---------------------------------------------------------------------------
__global__ __launch_bounds__(256) void aggregate_bf16(
    const unsigned short* __restrict__ in, unsigned short* __restrict__ out,
    const int* __restrict__ offs, const int* __restrict__ sorted_src) {
    int node = blockIdx.x * 4 + (threadIdx.x >> 6);
    if (node >= N_NODES) return;
    int lane = threadIdx.x & 63;
    int beg = offs[node], end = offs[node + 1];
    float a0 = 0.f, a1 = 0.f, a2 = 0.f, a3 = 0.f;
    for (int j = beg; j < end; ++j) {
        int s = sorted_src[j];
        ushort4 v = *(const ushort4*)(in + (size_t)s * D + lane * 4);
        a0 += bf2f(v.x); a1 += bf2f(v.y); a2 += bf2f(v.z); a3 += bf2f(v.w);
    }
    float inv = 1.0f / fmaxf((float)(end - beg), 1.0f);
    ushort4 r;
    r.x = f2bf(a0 * inv); r.y = f2bf(a1 * inv);
    r.z = f2bf(a2 * inv); r.w = f2bf(a3 * inv);
    *(ushort4*)(out + (size_t)node * D + lane * 4) = r;
}

// ---------------------------------------------------------------------------
// MFMA GEMM, one-barrier structure: out = [A0|A1] @ Bp + bias, K=512.
// BM=64, BN=256, 4 waves; the FULL 64x512 A-tile (64 KB) is staged into LDS
// via 16 global_load_lds(16B)/thread + ONE __syncthreads, then 256 MFMAs per
// wave run with no further barriers (B-frags from the L2-resident packed
// buffer, prefetchable inside the unbarriered loop).
// LDS layout: [half][row][256] bf16, 16B chunks XOR-swizzled by (row&7) so
// frag ds_read_b128 spreads over all 32 banks (row stride 512 B would
// otherwise land all 16 rows on the same bank group; padding is impossible
// with global_load_lds lane-contiguity).
// ---------------------------------------------------------------------------
__global__ __launch_bounds__(256) void gemm_mfma(
    const unsigned short* __restrict__ A0, const unsigned short* __restrict__ A1,
    const unsigned short* __restrict__ Bp, const float* __restrict__ bias,
    void* __restrict__ outp, int relu, int out_bf16) {
    __shared__ unsigned short As[2 * 64 * 256];   // 64 KB
    const int m0 = blockIdx.x * 64;
    const int t = threadIdx.x;
    const int wave = t >> 6, lane = t & 63;
    const int quad = lane >> 4, l16 = lane & 15;

    // ---- stage whole A tile: 4096 16B-chunks, 16 per thread ----
#pragma unroll
    for (int j = 0; j < 16; ++j) {
        int L  = j * 256 + t;          // LDS chunk index 0..4095
        int hr = L >> 5;               // 0..127 : half*64 + row
        int h  = hr >> 6;
        int r  = hr & 63;
        int cs = L & 31;               // stored chunk within row
        int cc = cs ^ (r & 7);         // logical 16B chunk (8 bf16 cols)
        int grow = m0 + r;
        if (grow >= N_NODES) grow = N_NODES - 1;   // clamp; never stored
        const unsigned short* gp =
            (h ? A1 : A0) + (size_t)grow * D + cc * 8;
        lds_b* ldst = (lds_b*)((char*)As + ((size_t)(j * 256 + wave * 64)) * 16);
        __builtin_amdgcn_global_load_lds((glob_b*)gp, ldst, 16, 0, 0);
    }
    __syncthreads();

    // ---- compute: no more barriers ----
    f32x4 acc[4][4] = {};
    const short8* Bp8 = (const short8*)Bp;
#pragma unroll 2
    for (int kb = 0; kb < 16; ++kb) {
        const int half = kb >> 3, kbl = kb & 7;
        short8 af[4], bf[4];
#pragma unroll
        for (int ni = 0; ni < 4; ++ni)
            bf[ni] = Bp8[(size_t)((wave * 4 + ni) * 16 + kb) * 64 + lane];
#pragma unroll
        for (int mi = 0; mi < 4; ++mi) {
            int row = mi * 16 + l16;
            int cs = (kbl * 4 + quad) ^ (row & 7);
            af[mi] = *(const short8*)((const char*)As +
                        (size_t)(((half * 64 + row) * 32 + cs) * 16));
        }
#pragma unroll
        for (int mi = 0; mi < 4; ++mi)
#pragma unroll
            for (int ni = 0; ni < 4; ++ni)
                acc[mi][ni] = __builtin_amdgcn_mfma_f32_16x16x32_bf16(
                    af[mi], bf[ni], acc[mi][ni], 0, 0, 0);
    }

    // ---- epilogue ----
    unsigned short* ob = (unsigned short*)outp;
    float* of = (float*)outp;
#pragma unroll
    for (int ni = 0; ni < 4; ++ni) {
        const int col = wave * 64 + ni * 16 + l16;
        const float bcol = bias[col];
#pragma unroll
        for (int mi = 0; mi < 4; ++mi) {
#pragma unroll
            for (int r = 0; r < 4; ++r) {
                int row = m0 + mi * 16 + quad * 4 + r;
                if (row < N_NODES) {
                    float v = acc[mi][ni][r] + bcol;
                    if (relu) v = fmaxf(v, 0.f);
                    if (out_bf16) ob[(size_t)row * D + col] = f2bf(v);
                    else          of[(size_t)row * D + col] = v;
                }
            }
        }
    }
}

// ---------------------------------------------------------------------------
extern "C" void kernel_launch(void* const* d_in, const int* in_sizes, int n_in,
                              void* d_out, int out_size, void* d_ws, size_t ws_size,
                              hipStream_t stream) {
    const float* x    = (const float*)d_in[0];
    const int*   ei   = (const int*)d_in[1];   // int32 on device!
    const float* W_l1 = (const float*)d_in[2];
    const float* b1   = (const float*)d_in[3];
    const float* W_r1 = (const float*)d_in[4];
    const float* W_l2 = (const float*)d_in[5];
    const float* b2   = (const float*)d_in[6];
    const float* W_r2 = (const float*)d_in[7];
    float* out = (float*)d_out;

    const int* src = ei;
    const int* tgt = ei + N_EDGES;

    char* w = (char*)d_ws;
    size_t o = 0;
    auto alloc = [&](size_t bytes) {
        size_t p = o;
        o = (o + bytes + 255) & ~(size_t)255;
        return p;
    };
    int* cnt        = (int*)(w + alloc((size_t)N_NODES * 4));
    int* offs       = (int*)(w + alloc((size_t)(N_NODES + 1) * 4));
    int* cursor     = (int*)(w + alloc((size_t)N_NODES * 4));
    int* bsum       = (int*)(w + alloc(512 * 4));
    int* sorted_src = (int*)(w + alloc((size_t)N_EDGES * 4));
    unsigned short* xb   = (unsigned short*)(w + alloc((size_t)N_NODES * D * 2));
    unsigned short* hb   = (unsigned short*)(w + alloc((size_t)N_NODES * D * 2));
    unsigned short* aggb = (unsigned short*)(w + alloc((size_t)N_NODES * D * 2));
    unsigned short* Bp1  = (unsigned short*)(w + alloc((size_t)512 * D * 2));
    unsigned short* Bp2  = (unsigned short*)(w + alloc((size_t)512 * D * 2));
    (void)ws_size; (void)in_sizes; (void)n_in; (void)out_size;

    hipMemsetAsync(cnt, 0, (size_t)N_NODES * 4, stream);

    const int EB = (N_EDGES + 255) / 256;
    count_kernel<<<EB, 256, 0, stream>>>(tgt, cnt);
    scan1_kernel<<<SCAN_BLOCKS, 256, 0, stream>>>(cnt, offs, bsum);
    scan2_kernel<<<1, 512, 0, stream>>>(bsum);
    scan3_kernel<<<SCAN_BLOCKS, 256, 0, stream>>>(offs, bsum);
    cursor_kernel<<<SCAN_BLOCKS, 256, 0, stream>>>(offs, cursor);
    fill_kernel<<<EB, 256, 0, stream>>>(src, tgt, cursor, sorted_src);

    // bf16 conversions / weight packing
    const int n8 = N_NODES * D / 8;
    convert_kernel<<<(n8 + 255) / 256, 256, 0, stream>>>(x, xb, n8);
    pack_b_kernel<<<64, 256, 0, stream>>>(W_l1, W_r1, Bp1);
    pack_b_kernel<<<64, 256, 0, stream>>>(W_l2, W_r2, Bp2);

    const int AGG_B  = (N_NODES + 3) / 4;        // 25000
    const int GEMM_B = (N_NODES + 63) / 64;      // 1563

    // Layer 1
    aggregate_bf16<<<AGG_B, 256, 0, stream>>>(xb, aggb, offs, sorted_src);
    gemm_mfma<<<GEMM_B, 256, 0, stream>>>(aggb, xb, Bp1, b1, hb, 1, 1);

    // Layer 2
    aggregate_bf16<<<AGG_B, 256, 0, stream>>>(hb, aggb, offs, sorted_src);
    gemm_mfma<<<GEMM_B, 256, 0, stream>>>(aggb, hb, Bp2, b2, out, 0, 0);
}